// Round 5
// baseline (638.840 us; speedup 1.0000x reference)
//
#include <hip/hip_runtime.h>
#include <hip/hip_cooperative_groups.h>

namespace cg = cooperative_groups;

#define BLK 256
#define LBLK 256   // layer kernel: 8 threads per node, 32 nodes/block
#define CH 1024    // scan chunk (N=200000 -> 196 chunks, <= 256)
#define SGRID 1024 // cooperative setup grid (4 blocks/CU, safely co-resident)

// ---------------- bf16 helpers ----------------
__device__ __forceinline__ unsigned short f2bf(float f) {
    unsigned u = __float_as_uint(f);
    u += 0x7FFFu + ((u >> 16) & 1u);       // round-to-nearest-even
    return (unsigned short)(u >> 16);
}
__device__ __forceinline__ float bf2f(unsigned short h) {
    return __uint_as_float((unsigned)h << 16);
}
__device__ __forceinline__ ushort4 pack4(float4 f) {
    ushort4 h; h.x = f2bf(f.x); h.y = f2bf(f.y); h.z = f2bf(f.z); h.w = f2bf(f.w);
    return h;
}
// 4 bf16 packed in uint2 -> float4 (low ushort = even dim)
__device__ __forceinline__ float4 unpack4u(uint2 u) {
    return make_float4(__uint_as_float(u.x << 16), __uint_as_float(u.x & 0xffff0000u),
                       __uint_as_float(u.y << 16), __uint_as_float(u.y & 0xffff0000u));
}
__device__ __forceinline__ unsigned pack2(float lo, float hi) {
    return (unsigned)f2bf(lo) | ((unsigned)f2bf(hi) << 16);
}

// ---------------- fused setup (cooperative) ----------------
// One kernel, 5 phases with grid-wide syncs (replaces memset + k_deg +
// k_scan1 + k_scan2 + k_convfill -> removes 4 dispatch boundaries and
// keeps deg hot in L2 across count -> scan -> fill):
//  P0 zero deg | P1 deg count + per-edge rank (atomics) | P2 chunk sums
//  P3 chunk-prefix + local scan -> row_off | P4 csr fill + embs convert
__global__ __launch_bounds__(BLK) void k_setup(
    const int* __restrict__ src, const int* __restrict__ dst,
    const float2* __restrict__ attrs,
    int* __restrict__ deg, int* __restrict__ rank, int* __restrict__ row_off,
    int* __restrict__ partials, uint2* __restrict__ csr,
    const float4* __restrict__ emb4, ushort4* __restrict__ embs,
    int N, int E, int nb, int N16) {
    cg::grid_group grid = cg::this_grid();
    const int t = threadIdx.x;
    const int gtid = blockIdx.x * BLK + t;
    const int gsize = gridDim.x * BLK;
    __shared__ int sp[BLK];
    __shared__ int sm[BLK];

    // P0: zero deg
    for (int i = gtid; i < N; i += gsize) deg[i] = 0;
    grid.sync();

    // P1: degree count + rank (one atomic per edge total)
    for (int e = gtid; e < E; e += gsize) rank[e] = atomicAdd(&deg[dst[e]], 1);
    grid.sync();

    // P2: per-chunk sums
    for (int c = blockIdx.x; c < nb; c += gridDim.x) {
        int i0 = c * CH + t * 4;
        int s = 0;
        if (i0 + 3 < N) {
            int4 v = *(const int4*)(deg + i0);
            s = (v.x + v.y) + (v.z + v.w);
        } else {
            for (int k = 0; k < 4; ++k) if (i0 + k < N) s += deg[i0 + k];
        }
        sm[t] = s;
        __syncthreads();
        for (int off = BLK / 2; off > 0; off >>= 1) {
            if (t < off) sm[t] += sm[t + off];
            __syncthreads();
        }
        if (t == 0) partials[c] = sm[0];
        __syncthreads();
    }
    grid.sync();

    // P3: redundant prefix of partials + local scan -> row_off
    for (int c = blockIdx.x; c < nb; c += gridDim.x) {
        sp[t] = (t < nb) ? partials[t] : 0;
        __syncthreads();
        for (int off = 1; off < BLK; off <<= 1) {
            int add = (t >= off) ? sp[t - off] : 0;
            __syncthreads();
            sp[t] += add;
            __syncthreads();
        }
        int base = (c == 0) ? 0 : sp[c - 1];
        if (c == 0 && t == 0) row_off[N] = E;
        int i0 = c * CH + t * 4;
        int v0 = 0, v1 = 0, v2 = 0, v3 = 0;
        if (i0 + 3 < N) {
            int4 v = *(const int4*)(deg + i0);
            v0 = v.x; v1 = v.y; v2 = v.z; v3 = v.w;
        } else {
            if (i0     < N) v0 = deg[i0];
            if (i0 + 1 < N) v1 = deg[i0 + 1];
            if (i0 + 2 < N) v2 = deg[i0 + 2];
        }
        int tot = (v0 + v1) + (v2 + v3);
        sm[t] = tot;
        __syncthreads();
        for (int off = 1; off < BLK; off <<= 1) {
            int add = (t >= off) ? sm[t - off] : 0;
            __syncthreads();
            sm[t] += add;
            __syncthreads();
        }
        int excl = base + sm[t] - tot;
        int4 r;
        r.x = excl;
        r.y = excl + v0;
        r.z = excl + v0 + v1;
        r.w = excl + v0 + v1 + v2;
        if (i0 + 3 < N) {
            *(int4*)(row_off + i0) = r;
        } else {
            if (i0     < N) row_off[i0]     = r.x;
            if (i0 + 1 < N) row_off[i0 + 1] = r.y;
            if (i0 + 2 < N) row_off[i0 + 2] = r.z;
        }
        __syncthreads();
    }
    grid.sync();

    // P4: atomic-free CSR fill + embs = bf16(dinv[v] * emb[v])
    for (int e = gtid; e < E; e += gsize) {
        int pos = row_off[dst[e]] + rank[e];
        float2 ar = attrs[e];
        csr[pos] = make_uint2((unsigned)src[e],
                              (unsigned)f2bf(ar.x) | ((unsigned)f2bf(ar.y) << 16));
    }
    for (int i = gtid; i < N16; i += gsize) {
        int d = deg[i >> 4];
        float dinv = (d > 0) ? rsqrtf((float)d) : 0.0f;
        float4 e = emb4[i];
        embs[i] = pack4(make_float4(dinv * e.x, dinv * e.y, dinv * e.z, dinv * e.w));
    }
}

// ---------------- per-layer kernel (round-4 best: 8 lanes/node) ----------------
// 8 threads per node, 8 dims each (uint4 = 8 bf16, 16 B/lane; one node-group's
// 8 lanes cover a full 128-B row -> one coalesced request).
// xs rows PRE-SCALED by dinv[src].
// x_new[v] = dinv[v] * (Σ w·xs[src]) / (Σ w + eps)

__device__ __forceinline__ float lrelu(float x) { return fmaxf(x, 0.01f * x); }

__device__ __forceinline__ void edge_w8(unsigned ar,
                                        const float4& awl, const float4& awh,
                                        const float4& rwl, const float4& rwh,
                                        float4& wl, float4& wh) {
    float a = bf2f((unsigned short)(ar & 0xffffu));
    float r = bf2f((unsigned short)(ar >> 16));
    wl.x = __expf(lrelu(a * awl.x) + lrelu(r * rwl.x));
    wl.y = __expf(lrelu(a * awl.y) + lrelu(r * rwl.y));
    wl.z = __expf(lrelu(a * awl.z) + lrelu(r * rwl.z));
    wl.w = __expf(lrelu(a * awl.w) + lrelu(r * rwl.w));
    wh.x = __expf(lrelu(a * awh.x) + lrelu(r * rwh.x));
    wh.y = __expf(lrelu(a * awh.y) + lrelu(r * rwh.y));
    wh.z = __expf(lrelu(a * awh.z) + lrelu(r * rwh.z));
    wh.w = __expf(lrelu(a * awh.w) + lrelu(r * rwh.w));
}

__device__ __forceinline__ void acc4u(float4& num, float4& den,
                                      const float4& w, uint2 xu, float g) {
    float4 x = unpack4u(xu);
    den.x += g * w.x; den.y += g * w.y; den.z += g * w.z; den.w += g * w.w;
    num.x += g * w.x * x.x;
    num.y += g * w.y * x.y;
    num.z += g * w.z * x.z;
    num.w += g * w.w * x.w;
}

__device__ __forceinline__ void acc8(float4& numl, float4& denl,
                                     float4& numh, float4& denh,
                                     const float4& wl, const float4& wh,
                                     const uint4& h, float g) {
    acc4u(numl, denl, wl, make_uint2(h.x, h.y), g);
    acc4u(numh, denh, wh, make_uint2(h.z, h.w), g);
}

template<int MODE>
__global__ __launch_bounds__(LBLK) void k_layer(
    const uint4* __restrict__ xs8, const uint2* __restrict__ csr,
    const int* __restrict__ row_off,
    const float4* __restrict__ aw4, const float4* __restrict__ rw4,
    const float4* __restrict__ emb4,
    const uint4* __restrict__ xsA8, const uint4* __restrict__ xsB8,
    uint4* __restrict__ xsout8, float4* __restrict__ out4, int N) {
    const int t = threadIdx.x;
    const int d8 = t & 7;
    const int v = blockIdx.x * (LBLK / 8) + (t >> 3);
    if (v >= N) return;

    const float4 awl = aw4[2 * d8],     rwl = rw4[2 * d8];
    const float4 awh = aw4[2 * d8 + 1], rwh = rw4[2 * d8 + 1];
    const int s0 = row_off[v];
    const int s1 = row_off[v + 1];

    float4 numl = {0.f, 0.f, 0.f, 0.f}, denl = {0.f, 0.f, 0.f, 0.f};
    float4 numh = {0.f, 0.f, 0.f, 0.f}, denh = {0.f, 0.f, 0.f, 0.f};

    for (int i = s0; i < s1; i += 4) {
        const int last = s1 - 1;
        uint2 e0 = csr[i];
        uint2 e1 = csr[min(i + 1, last)];
        uint2 e2 = csr[min(i + 2, last)];
        uint2 e3 = csr[min(i + 3, last)];
        uint4 h0 = xs8[(size_t)e0.x * 8 + d8];
        uint4 h1 = xs8[(size_t)e1.x * 8 + d8];
        uint4 h2 = xs8[(size_t)e2.x * 8 + d8];
        uint4 h3 = xs8[(size_t)e3.x * 8 + d8];
        float4 w0l, w0h, w1l, w1h, w2l, w2h, w3l, w3h;
        edge_w8(e0.y, awl, awh, rwl, rwh, w0l, w0h);
        edge_w8(e1.y, awl, awh, rwl, rwh, w1l, w1h);
        edge_w8(e2.y, awl, awh, rwl, rwh, w2l, w2h);
        edge_w8(e3.y, awl, awh, rwl, rwh, w3l, w3h);
        float g1 = (i + 1 < s1) ? 1.0f : 0.0f;
        float g2 = (i + 2 < s1) ? 1.0f : 0.0f;
        float g3 = (i + 3 < s1) ? 1.0f : 0.0f;
        acc8(numl, denl, numh, denh, w0l, w0h, h0, 1.0f);
        acc8(numl, denl, numh, denh, w1l, w1h, h1, g1);
        acc8(numl, denl, numh, denh, w2l, w2h, h2, g2);
        acc8(numl, denl, numh, denh, w3l, w3h, h3, g3);
    }

    float4 xr0, xr1;   // raw ratio, before dinv[v] scaling
    xr0.x = numl.x / (denl.x + 1e-16f);
    xr0.y = numl.y / (denl.y + 1e-16f);
    xr0.z = numl.z / (denl.z + 1e-16f);
    xr0.w = numl.w / (denl.w + 1e-16f);
    xr1.x = numh.x / (denh.x + 1e-16f);
    xr1.y = numh.y / (denh.y + 1e-16f);
    xr1.z = numh.z / (denh.z + 1e-16f);
    xr1.w = numh.w / (denh.w + 1e-16f);
    const int dv = s1 - s0;
    const float dinv = (dv > 0) ? rsqrtf((float)dv) : 0.0f;
    if (MODE == 2) {
        const float sd = (dv > 0) ? sqrtf((float)dv) : 0.0f;
        const size_t of = (size_t)v * 16 + 2 * d8;   // float4 index
        const size_t o8 = (size_t)v * 8 + d8;        // uint4 (8-bf16) index
        float4 e0 = emb4[of];
        float4 e1 = emb4[of + 1];
        uint4 Au = xsA8[o8];
        uint4 Bu = xsB8[o8];
        float4 A0 = unpack4u(make_uint2(Au.x, Au.y));
        float4 A1 = unpack4u(make_uint2(Au.z, Au.w));
        float4 B0 = unpack4u(make_uint2(Bu.x, Bu.y));
        float4 B1 = unpack4u(make_uint2(Bu.z, Bu.w));
        float4 r0, r1;
        r0.x = (e0.x + sd * (A0.x + B0.x) + dinv * xr0.x) * 0.25f;
        r0.y = (e0.y + sd * (A0.y + B0.y) + dinv * xr0.y) * 0.25f;
        r0.z = (e0.z + sd * (A0.z + B0.z) + dinv * xr0.z) * 0.25f;
        r0.w = (e0.w + sd * (A0.w + B0.w) + dinv * xr0.w) * 0.25f;
        r1.x = (e1.x + sd * (A1.x + B1.x) + dinv * xr1.x) * 0.25f;
        r1.y = (e1.y + sd * (A1.y + B1.y) + dinv * xr1.y) * 0.25f;
        r1.z = (e1.z + sd * (A1.z + B1.z) + dinv * xr1.z) * 0.25f;
        r1.w = (e1.w + sd * (A1.w + B1.w) + dinv * xr1.w) * 0.25f;
        out4[of]     = r0;
        out4[of + 1] = r1;
    } else {
        const float s = dinv * dinv;   // store dinv[v] * x_new = dinv^2 * xr
        uint4 pkt;
        pkt.x = pack2(s * xr0.x, s * xr0.y);
        pkt.y = pack2(s * xr0.z, s * xr0.w);
        pkt.z = pack2(s * xr1.x, s * xr1.y);
        pkt.w = pack2(s * xr1.z, s * xr1.w);
        xsout8[(size_t)v * 8 + d8] = pkt;
    }
}

// ---------------- launch ----------------

extern "C" void kernel_launch(void* const* d_in, const int* in_sizes, int n_in,
                              void* d_out, int out_size, void* d_ws, size_t ws_size,
                              hipStream_t stream) {
    const int*   ei    = (const int*)d_in[0];
    const float* attrs = (const float*)d_in[1];
    const float* emb   = (const float*)d_in[2];
    const float* a_att = (const float*)d_in[3];
    const float* r_att = (const float*)d_in[4];

    const int E = in_sizes[0] / 2;
    const int N = in_sizes[2] / 64;
    const int* src = ei;
    const int* dst = ei + E;

    char* ws = (char*)d_ws;
    size_t off = 0;
    auto alloc = [&](size_t bytes) {
        void* p = ws + off;
        off += (bytes + 255) & ~(size_t)255;
        return p;
    };
    int*     deg      = (int*)alloc((size_t)N * 4);
    int*     rank     = (int*)alloc((size_t)E * 4);
    int*     row_off  = (int*)alloc((size_t)(N + 1) * 4);
    int*     partials = (int*)alloc((size_t)BLK * 4);
    uint2*   csr      = (uint2*)alloc((size_t)E * 8);
    ushort4* embs     = (ushort4*)alloc((size_t)N * 16 * 8);
    ushort4* xsA      = (ushort4*)alloc((size_t)N * 16 * 8);
    ushort4* xsB      = (ushort4*)alloc((size_t)N * 16 * 8);
    float4*  out      = (float4*)d_out;

    int nb  = (N + CH - 1) / CH;   // 196 for N=200000 (must be <= 256)
    int N16 = N * 16;

    const float4* emb4 = (const float4*)emb;
    const float4* aw4  = (const float4*)a_att;
    const float4* rw4  = (const float4*)r_att;

    // fused cooperative setup (replaces memset + 4 kernels)
    {
        void* args[] = {
            (void*)&src, (void*)&dst, (void*)&attrs,
            (void*)&deg, (void*)&rank, (void*)&row_off,
            (void*)&partials, (void*)&csr,
            (void*)&emb4, (void*)&embs,
            (void*)&N, (void*)&E, (void*)&nb, (void*)&N16
        };
        hipLaunchCooperativeKernel((void*)k_setup, dim3(SGRID), dim3(BLK),
                                   args, 0, stream);
    }

    int gL = (N + (LBLK / 8) - 1) / (LBLK / 8);
    k_layer<0><<<gL, LBLK, 0, stream>>>((const uint4*)embs, csr, row_off, aw4,      rw4,
                                        nullptr, nullptr, nullptr, (uint4*)xsA, nullptr, N);
    k_layer<1><<<gL, LBLK, 0, stream>>>((const uint4*)xsA,  csr, row_off, aw4 + 16, rw4 + 16,
                                        nullptr, nullptr, nullptr, (uint4*)xsB, nullptr, N);
    k_layer<2><<<gL, LBLK, 0, stream>>>((const uint4*)xsB,  csr, row_off, aw4 + 32, rw4 + 32,
                                        emb4, (const uint4*)xsA, (const uint4*)xsB,
                                        nullptr, out, N);
}

// Round 6
// 267.268 us; speedup vs baseline: 2.3903x; 2.3903x over previous
//
#include <hip/hip_runtime.h>

#define BLK 256
#define LBLK 256    // layer kernel: 8 threads per node, 32 nodes/iteration/block
#define PGRID 2048  // persistent layer grid: 8 blocks/CU x 256 CUs
#define CH 1024     // scan chunk per block (N=200000 -> 196 blocks, <= 256)

// ---------------- bf16 helpers ----------------
__device__ __forceinline__ unsigned short f2bf(float f) {
    unsigned u = __float_as_uint(f);
    u += 0x7FFFu + ((u >> 16) & 1u);       // round-to-nearest-even
    return (unsigned short)(u >> 16);
}
__device__ __forceinline__ float bf2f(unsigned short h) {
    return __uint_as_float((unsigned)h << 16);
}
__device__ __forceinline__ ushort4 pack4(float4 f) {
    ushort4 h; h.x = f2bf(f.x); h.y = f2bf(f.y); h.z = f2bf(f.z); h.w = f2bf(f.w);
    return h;
}
// 4 bf16 packed in uint2 -> float4 (low ushort = even dim)
__device__ __forceinline__ float4 unpack4u(uint2 u) {
    return make_float4(__uint_as_float(u.x << 16), __uint_as_float(u.x & 0xffff0000u),
                       __uint_as_float(u.y << 16), __uint_as_float(u.y & 0xffff0000u));
}
__device__ __forceinline__ unsigned pack2(float lo, float hi) {
    return (unsigned)f2bf(lo) | ((unsigned)f2bf(hi) << 16);
}

// ---------------- setup kernels (reverted to proven R0/R4 versions) ----------------

__global__ void k_deg(const int* __restrict__ dst, int* __restrict__ deg,
                      int* __restrict__ rank, int E) {
    int e = blockIdx.x * blockDim.x + threadIdx.x;
    if (e < E) rank[e] = atomicAdd(&deg[dst[e]], 1);
}

__global__ void k_scan1(const int* __restrict__ deg, int* __restrict__ partials, int N) {
    __shared__ int sm[BLK];
    int i0 = blockIdx.x * CH + threadIdx.x * 4;
    int s = 0;
    if (i0 + 3 < N) {
        int4 v = *(const int4*)(deg + i0);
        s = (v.x + v.y) + (v.z + v.w);
    } else {
        for (int k = 0; k < 4; ++k) if (i0 + k < N) s += deg[i0 + k];
    }
    sm[threadIdx.x] = s;
    __syncthreads();
    for (int off = BLK / 2; off > 0; off >>= 1) {
        if (threadIdx.x < off) sm[threadIdx.x] += sm[threadIdx.x + off];
        __syncthreads();
    }
    if (threadIdx.x == 0) partials[blockIdx.x] = sm[0];
}

__global__ void k_scan2(const int* __restrict__ deg, const int* __restrict__ partials,
                        int* __restrict__ row_off, int N, int E, int nb) {
    __shared__ int sp[BLK];
    __shared__ int sm[BLK];
    int b = blockIdx.x, t = threadIdx.x;
    sp[t] = (t < nb) ? partials[t] : 0;
    __syncthreads();
    for (int off = 1; off < BLK; off <<= 1) {
        int add = (t >= off) ? sp[t - off] : 0;
        __syncthreads();
        sp[t] += add;
        __syncthreads();
    }
    int base = (b == 0) ? 0 : sp[b - 1];
    if (b == 0 && t == 0) row_off[N] = E;
    int i0 = b * CH + t * 4;
    int v0 = 0, v1 = 0, v2 = 0, v3 = 0;
    if (i0 + 3 < N) {
        int4 v = *(const int4*)(deg + i0);
        v0 = v.x; v1 = v.y; v2 = v.z; v3 = v.w;
    } else {
        if (i0     < N) v0 = deg[i0];
        if (i0 + 1 < N) v1 = deg[i0 + 1];
        if (i0 + 2 < N) v2 = deg[i0 + 2];
    }
    int tot = (v0 + v1) + (v2 + v3);
    sm[t] = tot;
    __syncthreads();
    for (int off = 1; off < BLK; off <<= 1) {
        int add = (t >= off) ? sm[t - off] : 0;
        __syncthreads();
        sm[t] += add;
        __syncthreads();
    }
    int excl = base + sm[t] - tot;
    int4 r;
    r.x = excl;
    r.y = excl + v0;
    r.z = excl + v0 + v1;
    r.w = excl + v0 + v1 + v2;
    if (i0 + 3 < N) {
        *(int4*)(row_off + i0) = r;
    } else {
        if (i0     < N) row_off[i0]     = r.x;
        if (i0 + 1 < N) row_off[i0 + 1] = r.y;
        if (i0 + 2 < N) row_off[i0 + 2] = r.z;
    }
}

__global__ void k_convfill(const int* __restrict__ src, const int* __restrict__ dst,
                           const float2* __restrict__ attrs, const int* __restrict__ row_off,
                           const int* __restrict__ rank, const int* __restrict__ deg,
                           uint2* __restrict__ csr, const float4* __restrict__ emb4,
                           ushort4* __restrict__ embs, int E, int N16, int gF) {
    int b = blockIdx.x;
    if (b < gF) {
        int e = b * BLK + threadIdx.x;
        if (e >= E) return;
        int pos = row_off[dst[e]] + rank[e];
        float2 ar = attrs[e];
        csr[pos] = make_uint2((unsigned)src[e],
                              (unsigned)f2bf(ar.x) | ((unsigned)f2bf(ar.y) << 16));
    } else {
        int i = (b - gF) * BLK + threadIdx.x;
        if (i >= N16) return;
        int d = deg[i >> 4];
        float dinv = (d > 0) ? rsqrtf((float)d) : 0.0f;
        float4 e = emb4[i];
        embs[i] = pack4(make_float4(dinv * e.x, dinv * e.y, dinv * e.z, dinv * e.w));
    }
}

// ---------------- per-layer kernel ----------------
// PERSISTENT grid-stride version of the round-4 kernel: exactly PGRID blocks
// (8 blocks/CU) stay resident for the whole dispatch, so resident node-chains
// are ~2-3x the dispatch-limited R0/R4 runs (the counter invariant across
// R0/R1/R4 was ~18k chains in flight at 28-54% occupancy; this pins ~50k).
// 8 threads per node, 8 dims each (uint4 = 8 bf16, 16 B/lane; one node-group's
// 8 lanes cover a full 128-B row -> one coalesced request).
// xs rows PRE-SCALED by dinv[src].
// x_new[v] = dinv[v] * (Σ w·xs[src]) / (Σ w + eps)

__device__ __forceinline__ float lrelu(float x) { return fmaxf(x, 0.01f * x); }

__device__ __forceinline__ void edge_w8(unsigned ar,
                                        const float4& awl, const float4& awh,
                                        const float4& rwl, const float4& rwh,
                                        float4& wl, float4& wh) {
    float a = bf2f((unsigned short)(ar & 0xffffu));
    float r = bf2f((unsigned short)(ar >> 16));
    wl.x = __expf(lrelu(a * awl.x) + lrelu(r * rwl.x));
    wl.y = __expf(lrelu(a * awl.y) + lrelu(r * rwl.y));
    wl.z = __expf(lrelu(a * awl.z) + lrelu(r * rwl.z));
    wl.w = __expf(lrelu(a * awl.w) + lrelu(r * rwl.w));
    wh.x = __expf(lrelu(a * awh.x) + lrelu(r * rwh.x));
    wh.y = __expf(lrelu(a * awh.y) + lrelu(r * rwh.y));
    wh.z = __expf(lrelu(a * awh.z) + lrelu(r * rwh.z));
    wh.w = __expf(lrelu(a * awh.w) + lrelu(r * rwh.w));
}

__device__ __forceinline__ void acc4u(float4& num, float4& den,
                                      const float4& w, uint2 xu, float g) {
    float4 x = unpack4u(xu);
    den.x += g * w.x; den.y += g * w.y; den.z += g * w.z; den.w += g * w.w;
    num.x += g * w.x * x.x;
    num.y += g * w.y * x.y;
    num.z += g * w.z * x.z;
    num.w += g * w.w * x.w;
}

__device__ __forceinline__ void acc8(float4& numl, float4& denl,
                                     float4& numh, float4& denh,
                                     const float4& wl, const float4& wh,
                                     const uint4& h, float g) {
    acc4u(numl, denl, wl, make_uint2(h.x, h.y), g);
    acc4u(numh, denh, wh, make_uint2(h.z, h.w), g);
}

template<int MODE>
__global__ __launch_bounds__(LBLK) void k_layer(
    const uint4* __restrict__ xs8, const uint2* __restrict__ csr,
    const int* __restrict__ row_off,
    const float4* __restrict__ aw4, const float4* __restrict__ rw4,
    const float4* __restrict__ emb4,
    const uint4* __restrict__ xsA8, const uint4* __restrict__ xsB8,
    uint4* __restrict__ xsout8, float4* __restrict__ out4, int N) {
    const int t = threadIdx.x;
    const int d8 = t & 7;

    const float4 awl = aw4[2 * d8],     rwl = rw4[2 * d8];
    const float4 awh = aw4[2 * d8 + 1], rwh = rw4[2 * d8 + 1];

    const int stride = gridDim.x * (LBLK / 8);
    for (int vb = blockIdx.x * (LBLK / 8); vb < N; vb += stride) {
        const int v = vb + (t >> 3);
        if (v >= N) continue;

        const int s0 = row_off[v];
        const int s1 = row_off[v + 1];

        float4 numl = {0.f, 0.f, 0.f, 0.f}, denl = {0.f, 0.f, 0.f, 0.f};
        float4 numh = {0.f, 0.f, 0.f, 0.f}, denh = {0.f, 0.f, 0.f, 0.f};

        for (int i = s0; i < s1; i += 4) {
            const int last = s1 - 1;
            uint2 e0 = csr[i];
            uint2 e1 = csr[min(i + 1, last)];
            uint2 e2 = csr[min(i + 2, last)];
            uint2 e3 = csr[min(i + 3, last)];
            uint4 h0 = xs8[(size_t)e0.x * 8 + d8];
            uint4 h1 = xs8[(size_t)e1.x * 8 + d8];
            uint4 h2 = xs8[(size_t)e2.x * 8 + d8];
            uint4 h3 = xs8[(size_t)e3.x * 8 + d8];
            float4 w0l, w0h, w1l, w1h, w2l, w2h, w3l, w3h;
            edge_w8(e0.y, awl, awh, rwl, rwh, w0l, w0h);
            edge_w8(e1.y, awl, awh, rwl, rwh, w1l, w1h);
            edge_w8(e2.y, awl, awh, rwl, rwh, w2l, w2h);
            edge_w8(e3.y, awl, awh, rwl, rwh, w3l, w3h);
            float g1 = (i + 1 < s1) ? 1.0f : 0.0f;
            float g2 = (i + 2 < s1) ? 1.0f : 0.0f;
            float g3 = (i + 3 < s1) ? 1.0f : 0.0f;
            acc8(numl, denl, numh, denh, w0l, w0h, h0, 1.0f);
            acc8(numl, denl, numh, denh, w1l, w1h, h1, g1);
            acc8(numl, denl, numh, denh, w2l, w2h, h2, g2);
            acc8(numl, denl, numh, denh, w3l, w3h, h3, g3);
        }

        float4 xr0, xr1;   // raw ratio, before dinv[v] scaling
        xr0.x = numl.x / (denl.x + 1e-16f);
        xr0.y = numl.y / (denl.y + 1e-16f);
        xr0.z = numl.z / (denl.z + 1e-16f);
        xr0.w = numl.w / (denl.w + 1e-16f);
        xr1.x = numh.x / (denh.x + 1e-16f);
        xr1.y = numh.y / (denh.y + 1e-16f);
        xr1.z = numh.z / (denh.z + 1e-16f);
        xr1.w = numh.w / (denh.w + 1e-16f);
        const int dv = s1 - s0;
        const float dinv = (dv > 0) ? rsqrtf((float)dv) : 0.0f;
        if (MODE == 2) {
            const float sd = (dv > 0) ? sqrtf((float)dv) : 0.0f;
            const size_t of = (size_t)v * 16 + 2 * d8;   // float4 index
            const size_t o8 = (size_t)v * 8 + d8;        // uint4 (8-bf16) index
            float4 e0 = emb4[of];
            float4 e1 = emb4[of + 1];
            uint4 Au = xsA8[o8];
            uint4 Bu = xsB8[o8];
            float4 A0 = unpack4u(make_uint2(Au.x, Au.y));
            float4 A1 = unpack4u(make_uint2(Au.z, Au.w));
            float4 B0 = unpack4u(make_uint2(Bu.x, Bu.y));
            float4 B1 = unpack4u(make_uint2(Bu.z, Bu.w));
            float4 r0, r1;
            r0.x = (e0.x + sd * (A0.x + B0.x) + dinv * xr0.x) * 0.25f;
            r0.y = (e0.y + sd * (A0.y + B0.y) + dinv * xr0.y) * 0.25f;
            r0.z = (e0.z + sd * (A0.z + B0.z) + dinv * xr0.z) * 0.25f;
            r0.w = (e0.w + sd * (A0.w + B0.w) + dinv * xr0.w) * 0.25f;
            r1.x = (e1.x + sd * (A1.x + B1.x) + dinv * xr1.x) * 0.25f;
            r1.y = (e1.y + sd * (A1.y + B1.y) + dinv * xr1.y) * 0.25f;
            r1.z = (e1.z + sd * (A1.z + B1.z) + dinv * xr1.z) * 0.25f;
            r1.w = (e1.w + sd * (A1.w + B1.w) + dinv * xr1.w) * 0.25f;
            out4[of]     = r0;
            out4[of + 1] = r1;
        } else {
            const float s = dinv * dinv;   // store dinv[v] * x_new = dinv^2 * xr
            uint4 pkt;
            pkt.x = pack2(s * xr0.x, s * xr0.y);
            pkt.y = pack2(s * xr0.z, s * xr0.w);
            pkt.z = pack2(s * xr1.x, s * xr1.y);
            pkt.w = pack2(s * xr1.z, s * xr1.w);
            xsout8[(size_t)v * 8 + d8] = pkt;
        }
    }
}

// ---------------- launch ----------------

extern "C" void kernel_launch(void* const* d_in, const int* in_sizes, int n_in,
                              void* d_out, int out_size, void* d_ws, size_t ws_size,
                              hipStream_t stream) {
    const int*   ei    = (const int*)d_in[0];
    const float* attrs = (const float*)d_in[1];
    const float* emb   = (const float*)d_in[2];
    const float* a_att = (const float*)d_in[3];
    const float* r_att = (const float*)d_in[4];

    const int E = in_sizes[0] / 2;
    const int N = in_sizes[2] / 64;
    const int* src = ei;
    const int* dst = ei + E;

    char* ws = (char*)d_ws;
    size_t off = 0;
    auto alloc = [&](size_t bytes) {
        void* p = ws + off;
        off += (bytes + 255) & ~(size_t)255;
        return p;
    };
    int*     deg      = (int*)alloc((size_t)N * 4);
    int*     rank     = (int*)alloc((size_t)E * 4);
    int*     row_off  = (int*)alloc((size_t)(N + 1) * 4);
    int*     partials = (int*)alloc((size_t)BLK * 4);
    uint2*   csr      = (uint2*)alloc((size_t)E * 8);
    ushort4* embs     = (ushort4*)alloc((size_t)N * 16 * 8);
    ushort4* xsA      = (ushort4*)alloc((size_t)N * 16 * 8);
    ushort4* xsB      = (ushort4*)alloc((size_t)N * 16 * 8);
    float4*  out      = (float4*)d_out;

    hipMemsetAsync(deg, 0, (size_t)N * 4, stream);

    int gE = (E + BLK - 1) / BLK;
    int nb = (N + CH - 1) / CH;                 // 196 for N=200000 (must be <= 256)
    int gF = gE;
    int gC = (N * 16 + BLK - 1) / BLK;

    k_deg     <<<gE, BLK, 0, stream>>>(dst, deg, rank, E);
    k_scan1   <<<nb, BLK, 0, stream>>>(deg, partials, N);
    k_scan2   <<<nb, BLK, 0, stream>>>(deg, partials, row_off, N, E, nb);
    k_convfill<<<gF + gC, BLK, 0, stream>>>(src, dst, (const float2*)attrs, row_off,
                                            rank, deg, csr, (const float4*)emb,
                                            embs, E, N * 16, gF);

    const float4* emb4 = (const float4*)emb;
    const float4* aw4  = (const float4*)a_att;
    const float4* rw4  = (const float4*)r_att;

    int gL = (N + (LBLK / 8) - 1) / (LBLK / 8);
    if (gL > PGRID) gL = PGRID;   // persistent: 8 blocks/CU, grid-stride the rest
    k_layer<0><<<gL, LBLK, 0, stream>>>((const uint4*)embs, csr, row_off, aw4,      rw4,
                                        nullptr, nullptr, nullptr, (uint4*)xsA, nullptr, N);
    k_layer<1><<<gL, LBLK, 0, stream>>>((const uint4*)xsA,  csr, row_off, aw4 + 16, rw4 + 16,
                                        nullptr, nullptr, nullptr, (uint4*)xsB, nullptr, N);
    k_layer<2><<<gL, LBLK, 0, stream>>>((const uint4*)xsB,  csr, row_off, aw4 + 32, rw4 + 32,
                                        emb4, (const uint4*)xsA, (const uint4*)xsB,
                                        nullptr, out, N);
}